// Round 3
// baseline (165.600 us; speedup 1.0000x reference)
//
#include <hip/hip_runtime.h>

// VectorQuantizer: fp32 buffers, low-precision-valued data. in [32,64,64,64]
// NCHW, emb [512,64], out fp32. np-ref computes distances in fp32 -> argmin
// must match numpy bit-for-bit. Proven numerics (R5-R12, absmax 0.0):
// hi/lo bf16 split (exact products), max-domain filter acc' = dot - b2/2 via
// MFMA acc init; index packed in low 9 mantissa bits; med3/max top-3 net;
// ambiguity resolved by bit-exact numpy fp32 replica (top-2 re-rank, rare
// full rescan). HMARGIN 1.45e-4 (max domain), 1.8x the error bound.
// R13: (a) vq_prep was 2 blocks on 256 CUs (likely ~60us of the score's
// constant 64us gap over vq_mfma): now 128 blocks, coalesced; b2 combine via
// shfl_xor tree that replicates numpy pairwise-8 order bit-exactly.
// (b) vq_mfma de-synchronized: each wave owns 16 rows x ALL 512 cols
// (32 iters x 6 MFMA, same total), so top-3 completes in-wave; cross-wave
// LDS merge, wave0-only decision, atomic rescan queue, win[] all replaced by
// in-wave shuffles. Barriers 5 -> 2; waves drift freely between them.

#define NEMB 512
#define DIM 64
#define ROWS 64
#define HMARGIN 1.45e-4f  // margin in acc' = -c2/2 (max) domain

typedef unsigned int u32;
typedef unsigned short u16;
typedef __attribute__((ext_vector_type(8))) short bf16x8;
typedef __attribute__((ext_vector_type(4))) float f32x4;

__device__ __forceinline__ u32 f2bfbits(float f) {  // fp32 -> bf16 bits (RNE)
  u32 u = __float_as_uint(f);
  return (u + 0x7FFFu + ((u >> 16) & 1u)) >> 16;
}
__device__ __forceinline__ float bfbits2f(u32 b) {
  return __uint_as_float(b << 16);
}
__device__ __forceinline__ float fmed3(float a, float b, float c) {
  return __builtin_amdgcn_fmed3f(a, b, c);
}

// ---- prep: swizzled hi/lo bf16 codebook + exact numpy-replica b2 ----
// off(g,p,f,r,e) = g*2048 + p*1024 + f*512 + r*32 + e   (u16 units)
//   g=row>>4, r=row&15, p=plane(0 hi,1 lo), f=k>>5, e=k&31.
// R13: 128 blocks x 256 thr. swz: one thread per element (coalesced reads).
// b2: 8 threads/row; shfl_xor(1,2,4) tree == ((r0+r1)+(r2+r3))+((r4+r5)+(r6+r7))
// bit-exactly (lane j=0's left operand is its own partial at every step).
__global__ void vq_prep(const float* __restrict__ emb, u16* __restrict__ swz,
                        float* __restrict__ b2) {
#pragma clang fp contract(off)
  const int gtid = blockIdx.x * 256 + threadIdx.x;  // 0..32767
  {  // swz element task
    const int row = gtid >> 6, k = gtid & 63;
    const float ev = emb[gtid];
    const u32 h = f2bfbits(ev);
    const float res = ev - bfbits2f(h);  // exact (Sterbenz)
    u16* gb = swz + ((row >> 4) << 11) + ((row & 15) << 5);
    const int off2 = ((k >> 5) << 9) + (k & 31);
    gb[off2] = (u16)h;                     // hi plane
    gb[1024 + off2] = (u16)f2bfbits(res);  // lo plane
  }
  if (gtid < NEMB * 8) {  // b2 task: row = gtid>>3, j = gtid&7 (block-uniform)
    const int row = gtid >> 3, j = gtid & 7;
    const float* e = emb + (row << 6);
    float acc = e[j] * e[j];
#pragma unroll
    for (int i = 8; i < DIM; i += 8) acc = acc + e[i + j] * e[i + j];
    acc = acc + __shfl_xor(acc, 1);  // j=0: rr0+rr1
    acc = acc + __shfl_xor(acc, 2);  // j=0: (rr0+rr1)+(rr2+rr3)
    acc = acc + __shfl_xor(acc, 4);  // j=0: full pairwise-8 combine
    if (j == 0) b2[row] = acc;
  }
}

// ---- main kernel: 64 rows/block, 4 waves; wave wv owns rows [16wv,16wv+16)
// across ALL 512 cols. Wave-local top-3, decision, rescan, fold. ----
__global__ __launch_bounds__(256, 1) void vq_mfma(
    const float* __restrict__ in, const float* __restrict__ emb,
    const u16* __restrict__ swz, const float* __restrict__ b2g,
    float* __restrict__ out) {
#pragma clang fp contract(off)
  __shared__ float xs[ROWS][DIM + 2];
  __shared__ float b2s[NEMB];

  const int tid = threadIdx.x;
  const int blk = blockIdx.x;
  const int b = blk >> 6;
  const int hw0 = (blk & 63) << 6;
  const float* xbase = in + ((size_t)b << 18) + hw0;

  for (int i = tid; i < NEMB; i += 256) b2s[i] = b2g[i];

  {  // stage x tile (64 consecutive floats per wave = coalesced)
    const int h = tid & 63, cg = tid >> 6;
#pragma unroll
    for (int i = 0; i < 16; ++i) {
      const int c = cg + (i << 2);
      xs[h][c] = xbase[((size_t)c << 12) + h];
    }
  }
  __syncthreads();  // barrier 1 of 2

  const int lane = tid & 63;
  const int wv = tid >> 6;
  const int rowl = lane & 15;
  const int quad = lane >> 4;
  const int row0 = wv << 4;

  // A fragments for this wave's row-tile: A[m=lane&15][k=quad*8+j]
  bf16x8 ah[2], al[2];
#pragma unroll
  for (int f = 0; f < 2; ++f) {
    const float* xr = xs[row0 + rowl];
    const int k0 = (f << 5) + (quad << 3);
    bf16x8 vh, vl;
#pragma unroll
    for (int j = 0; j < 8; ++j) {
      const float xv = xr[k0 + j];
      const u32 h = f2bfbits(xv);
      const float res = xv - bfbits2f(h);  // exact
      vh[j] = (short)h;
      vl[j] = (short)f2bfbits(res);
    }
    ah[f] = vh;
    al[f] = vl;
  }

  // ---- single pass over ALL 512 cols: streaming top-3 MAXIMA of
  // acc' = dot - b2/2, index packed in low 9 mantissa bits ----
  float v1[4], v2[4], v3[4];
#pragma unroll
  for (int i = 0; i < 4; ++i) { v1[i] = -3.0e38f; v2[i] = -3.0e38f; v3[i] = -3.0e38f; }

  const u16* cbase = swz;
  const int off = (rowl << 5) + (quad << 3);

  // 2-deep prefetch: two register sets, manual 2-phase rolled loop
  bf16x8 Ah0 = *(const bf16x8*)(cbase + off);
  bf16x8 Ah1 = *(const bf16x8*)(cbase + 512 + off);
  bf16x8 Al0 = *(const bf16x8*)(cbase + 1024 + off);
  bf16x8 Al1 = *(const bf16x8*)(cbase + 1536 + off);
  bf16x8 Bh0 = *(const bf16x8*)(cbase + 2048 + off);
  bf16x8 Bh1 = *(const bf16x8*)(cbase + 2048 + 512 + off);
  bf16x8 Bl0 = *(const bf16x8*)(cbase + 2048 + 1024 + off);
  bf16x8 Bl1 = *(const bf16x8*)(cbase + 2048 + 1536 + off);

#define VQ_PHASE(TT, PH0, PH1, PL0, PL1)                                      \
  {                                                                           \
    const bf16x8 bh0 = PH0, bh1 = PH1, bl0 = PL0, bl1 = PL1;                  \
    const int tn = (TT) + 2 < 32 ? (TT) + 2 : (TT); /* clamped reload */      \
    const u16* gb = cbase + (tn << 11);                                       \
    PH0 = *(const bf16x8*)(gb + off);                                         \
    PH1 = *(const bf16x8*)(gb + 512 + off);                                   \
    PL0 = *(const bf16x8*)(gb + 1024 + off);                                  \
    PL1 = *(const bf16x8*)(gb + 1536 + off);                                  \
    const int n = ((TT) << 4) + rowl;                                         \
    const float nb2 = b2s[n] * -0.5f;                                         \
    const u32 nbits = (u32)n;                                                 \
    f32x4 acc = {nb2, nb2, nb2, nb2};                                         \
    acc = __builtin_amdgcn_mfma_f32_16x16x32_bf16(ah[0], bh0, acc, 0, 0, 0);  \
    acc = __builtin_amdgcn_mfma_f32_16x16x32_bf16(ah[1], bh1, acc, 0, 0, 0);  \
    acc = __builtin_amdgcn_mfma_f32_16x16x32_bf16(ah[0], bl0, acc, 0, 0, 0);  \
    acc = __builtin_amdgcn_mfma_f32_16x16x32_bf16(ah[1], bl1, acc, 0, 0, 0);  \
    acc = __builtin_amdgcn_mfma_f32_16x16x32_bf16(al[0], bh0, acc, 0, 0, 0);  \
    acc = __builtin_amdgcn_mfma_f32_16x16x32_bf16(al[1], bh1, acc, 0, 0, 0);  \
    _Pragma("unroll") for (int r = 0; r < 4; ++r) {                           \
      const float cp =                                                        \
          __uint_as_float((__float_as_uint(acc[r]) & 0xFFFFFE00u) | nbits);   \
      v3[r] = fmed3(v2[r], cp, v3[r]);                                        \
      v2[r] = fmed3(v1[r], cp, v2[r]);                                        \
      v1[r] = fmaxf(v1[r], cp);                                               \
    }                                                                         \
  }

#pragma unroll 1
  for (int t = 0; t < 32; t += 2) {
    VQ_PHASE(t, Ah0, Ah1, Al0, Al1);
    VQ_PHASE(t + 1, Bh0, Bh1, Bl0, Bl1);
  }
#undef VQ_PHASE

  // butterfly top-3 merge across the 16 column classes (max domain);
  // after this every lane holds the full top-3 for rows quad*4 + r
#pragma unroll
  for (int m = 1; m < 16; m <<= 1) {
#pragma unroll
    for (int i = 0; i < 4; ++i) {
      const float o1 = __shfl_xor(v1[i], m);
      const float o2 = __shfl_xor(v2[i], m);
      const float o3 = __shfl_xor(v3[i], m);
      v3[i] = fmed3(v2[i], o1, v3[i]);
      v2[i] = fmed3(v1[i], o1, v2[i]);
      v1[i] = fmaxf(v1[i], o1);
      v3[i] = fmed3(v2[i], o2, v3[i]);
      v2[i] = fmed3(v1[i], o2, v2[i]);
      v3[i] = fmaxf(v3[i], o3);
    }
  }

  // a2 numpy pairwise-8 replica for this lane's row (4x redundant, uniform)
  float a2row;
  {
    const float* x = xs[row0 + rowl];
    float rr[8];
#pragma unroll
    for (int j = 0; j < 8; ++j) {
      float acc = x[j] * x[j];
#pragma unroll
      for (int i = 8; i < DIM; i += 8) acc = acc + x[i + j] * x[i + j];
      rr[j] = acc;
    }
    a2row = ((rr[0] + rr[1]) + (rr[2] + rr[3])) + ((rr[4] + rr[5]) + (rr[6] + rr[7]));
  }

  // shuffle-transpose: lane L receives top-3 of row row0 + (L&15)
  float m1, m2v, m3;
  {
    const int srcl = ((lane >> 2) & 3) << 4;  // lane 16*((L&15)>>2)
    const int rm = lane & 3;
    float t0 = __shfl(v1[0], srcl), t1 = __shfl(v1[1], srcl);
    float t2 = __shfl(v1[2], srcl), t3 = __shfl(v1[3], srcl);
    m1 = rm == 0 ? t0 : rm == 1 ? t1 : rm == 2 ? t2 : t3;
    t0 = __shfl(v2[0], srcl); t1 = __shfl(v2[1], srcl);
    t2 = __shfl(v2[2], srcl); t3 = __shfl(v2[3], srcl);
    m2v = rm == 0 ? t0 : rm == 1 ? t1 : rm == 2 ? t2 : t3;
    t0 = __shfl(v3[0], srcl); t1 = __shfl(v3[1], srcl);
    t2 = __shfl(v3[2], srcl); t3 = __shfl(v3[3], srcl);
    m3 = rm == 0 ? t0 : rm == 1 ? t1 : rm == 2 ? t2 : t3;
  }

  // ---- per-lane decision (max domain), wave-local ----
  int jwin = 0;
  bool needFull = false;
  {
    const int j1 = (int)(__float_as_uint(m1) & 0x1FFu);
    const int j2 = (int)(__float_as_uint(m2v) & 0x1FFu);
    if (m2v < m1 - HMARGIN) {
      jwin = j1;  // unambiguous
    } else if (m3 < m1 - HMARGIN) {
      // true argmin in {j1,j2}: exact numpy fp32 re-rank, first-min tie rule
      const float* x = xs[row0 + rowl];
      const float* e1p = emb + (j1 << 6);
      const float* e2p = emb + (j2 << 6);
      float acc1 = 0.f, acc2 = 0.f;
#pragma unroll
      for (int j = 0; j < DIM; ++j) {
        acc1 = fmaf(x[j], e1p[j], acc1);
        acc2 = fmaf(x[j], e2p[j], acc2);
      }
      const float t1 = a2row + b2s[j1];
      const float t2 = a2row + b2s[j2];
      const float d1 = t1 - 2.0f * acc1;
      const float d2 = t2 - 2.0f * acc2;
      jwin = (d2 < d1 || (d2 == d1 && j2 < j1)) ? j2 : j1;
    } else {
      needFull = true;  // >=3 within margin: full exact rescan (rare)
    }
  }

  // ---- rare fallback: wave-cooperative bit-exact numpy fp32 rescan ----
  unsigned long long fmask = __ballot(needFull && lane < 16);
  while (fmask) {
    const int r = (int)__builtin_ctzll(fmask);
    fmask &= fmask - 1;
    const float a2v = __shfl(a2row, r);
    const float* x = xs[row0 + r];  // broadcast LDS reads
    float bd = 3.0e38f;
    int bi = 1 << 30;
#pragma unroll 1
    for (int c = 0; c < 8; ++c) {
      const int k = (c << 6) + lane;
      const float* e = emb + (k << 6);
      float acc = 0.f;
#pragma unroll
      for (int j = 0; j < DIM; ++j) acc = fmaf(x[j], e[j], acc);
      const float tt = a2v + b2s[k];  // fl(a2+b2)
      const float u = 2.0f * acc;     // fl(2ab)
      const float d = tt - u;         // fl(t-u)
      if (d < bd || (d == bd && k < bi)) { bd = d; bi = k; }
    }
#pragma unroll
    for (int m = 1; m < 64; m <<= 1) {  // numpy first-min tie rule
      const float od = __shfl_xor(bd, m);
      const int oi = __shfl_xor(bi, m);
      if (od < bd || (od == bd && oi < bi)) { bd = od; bi = oi; }
    }
    if (lane == r) jwin = bi;
  }

  {  // fold q into xs in place: wave-local, batched (16 concurrent emb rows)
    int wn[16];
#pragma unroll
    for (int r = 0; r < 16; ++r) wn[r] = __shfl(jwin, r);
    float qv[16];
#pragma unroll
    for (int r = 0; r < 16; ++r) qv[r] = emb[(wn[r] << 6) + lane];
#pragma unroll
    for (int r = 0; r < 16; ++r) {
      const float xv = xs[row0 + r][lane];
      xs[row0 + r][lane] = xv + (qv[r] - xv);  // fl(x + fl(q-x))
    }
  }
  __syncthreads();  // barrier 2 of 2

  {  // store: coalesced (lane = h)
    const int h = tid & 63, cg = tid >> 6;
    float* obase = out + ((size_t)b << 18) + hw0;
#pragma unroll
    for (int i = 0; i < 16; ++i) {
      const int c = cg + (i << 2);
      obase[((size_t)c << 12) + h] = xs[h][c];
    }
  }
}

// ---- fallback (R3, passed absmax 0.0): used only if ws too small ----
__global__ __launch_bounds__(256, 2) void vq_exact(
    const float* __restrict__ in, const float* __restrict__ emb,
    float* __restrict__ out, int nvec) {
#pragma clang fp contract(off)
  __shared__ float b2s[NEMB];
  for (int r = threadIdx.x; r < NEMB; r += 256) {
    const float* e = emb + r * DIM;
    float rr[8];
#pragma unroll
    for (int j = 0; j < 8; ++j) {
      float acc = e[j] * e[j];
#pragma unroll
      for (int i = 8; i < DIM; i += 8) acc = acc + e[i + j] * e[i + j];
      rr[j] = acc;
    }
    b2s[r] = ((rr[0] + rr[1]) + (rr[2] + rr[3])) + ((rr[4] + rr[5]) + (rr[6] + rr[7]));
  }
  __syncthreads();
  const int vec = blockIdx.x * 256 + threadIdx.x;
  if (vec >= nvec) return;
  const int b = vec >> 12, hw = vec & 4095;
  const float* xp = in + ((size_t)b << 18) + hw;
  float x[DIM];
#pragma unroll
  for (int j = 0; j < DIM; ++j) x[j] = xp[(size_t)j << 12];
  float a2;
  {
    float rr[8];
#pragma unroll
    for (int j = 0; j < 8; ++j) {
      float acc = x[j] * x[j];
#pragma unroll
      for (int i = 8; i < DIM; i += 8) acc = acc + x[i + j] * x[i + j];
      rr[j] = acc;
    }
    a2 = ((rr[0] + rr[1]) + (rr[2] + rr[3])) + ((rr[4] + rr[5]) + (rr[6] + rr[7]));
  }
  float best = 3.0e38f;
  int bi = 0;
  for (int k0 = 0; k0 < NEMB; k0 += 4) {
    const float *e0 = emb + ((k0 + 0) << 6), *e1 = emb + ((k0 + 1) << 6);
    const float *e2 = emb + ((k0 + 2) << 6), *e3 = emb + ((k0 + 3) << 6);
    float c0 = 0.f, c1 = 0.f, c2 = 0.f, c3 = 0.f;
#pragma unroll
    for (int j = 0; j < DIM; ++j) {
      const float xj = x[j];
      c0 = fmaf(xj, e0[j], c0); c1 = fmaf(xj, e1[j], c1);
      c2 = fmaf(xj, e2[j], c2); c3 = fmaf(xj, e3[j], c3);
    }
    float cc[4] = {c0, c1, c2, c3};
#pragma unroll
    for (int q = 0; q < 4; ++q) {
      const float t = a2 + b2s[k0 + q];
      const float u = 2.0f * cc[q];
      const float d = t - u;
      if (d < best) { best = d; bi = k0 + q; }
    }
  }
  const float* ew = emb + (bi << 6);
  float* op = out + ((size_t)b << 18) + hw;
#pragma unroll
  for (int c = 0; c < DIM; ++c) {
    const float xv = x[c];
    op[(size_t)c << 12] = xv + (ew[c] - xv);
  }
}

extern "C" void kernel_launch(void* const* d_in, const int* in_sizes, int n_in,
                              void* d_out, int out_size, void* d_ws, size_t ws_size,
                              hipStream_t stream) {
  const float* in;
  const float* emb;
  int in_elems;
  if (n_in >= 2 && in_sizes[0] == NEMB * DIM && in_sizes[1] != NEMB * DIM) {
    emb = (const float*)d_in[0]; in = (const float*)d_in[1]; in_elems = in_sizes[1];
  } else {
    in = (const float*)d_in[0]; emb = (const float*)d_in[1]; in_elems = in_sizes[0];
  }
  float* out = (float*)d_out;
  const int nvec = in_elems / DIM;
  const size_t swzB = (size_t)NEMB * DIM * 2 * sizeof(u16);  // hi+lo swizzled
  const size_t need = swzB + NEMB * sizeof(float);

  if (ws_size >= need && d_ws != nullptr && (nvec % ROWS) == 0 &&
      (in_elems % (DIM * 4096)) == 0) {
    u16* swz = (u16*)d_ws;
    float* b2 = (float*)((char*)d_ws + swzB);
    vq_prep<<<dim3(NEMB * DIM / 256), dim3(256), 0, stream>>>(emb, swz, b2);
    vq_mfma<<<dim3(nvec / ROWS), dim3(256), 0, stream>>>(in, emb, swz, b2, out);
  } else {
    vq_exact<<<dim3((nvec + 255) / 256), dim3(256), 0, stream>>>(in, emb, out, nvec);
  }
}

// Round 4
// 151.296 us; speedup vs baseline: 1.0945x; 1.0945x over previous
//
#include <hip/hip_runtime.h>

// VectorQuantizer: fp32 buffers, low-precision-valued data. in [32,64,64,64]
// NCHW, emb [512,64], out fp32. np-ref computes distances in fp32 -> argmin
// must match numpy bit-for-bit. Proven numerics (R5-R12, absmax 0.0):
// hi/lo bf16 split (exact products), max-domain filter acc' = dot - b2/2 via
// MFMA acc init; index packed in low 9 mantissa bits; med3/max top-3 net;
// ambiguity resolved by bit-exact numpy fp32 replica (top-2 re-rank, rare
// full rescan). HMARGIN 1.45e-4 (max domain), >1.7x the error bound
// (incl. <1e-6 from the R14 2x3 MFMA chain split).
// R13 post-mortem: score gap ~61us is fixed harness overhead (prep
// parallelization didn't move it); doubling per-wave codebook loads cost
// +30% -> hot loop is paced by codebook GLOBAL LOAD latency/issue.
// R14: back to R12 wave layout (col-half split, 2 row-tiles/wave) + stage
// the codebook through LDS with async global_load_lds double-buffering
// (8 chunks x 32 cols, 16KB/chunk both halves, 2 bufs). vq_prep re-permutes
// fragment 16B units into MFMA-lane order so staging is a LINEAR copy
// (wave-uniform base + lane*16) and ds_read_b128 is lane-consecutive
// (conflict-free). MFMA split into 2 chains of 3 (accA=-b2/2, accB=0, add).

#define NEMB 512
#define DIM 64
#define ROWS 64
#define HMARGIN 1.45e-4f  // margin in acc' = -c2/2 (max) domain

typedef unsigned int u32;
typedef unsigned short u16;
typedef __attribute__((ext_vector_type(8))) short bf16x8;
typedef __attribute__((ext_vector_type(4))) float f32x4;

__device__ __forceinline__ u32 f2bfbits(float f) {  // fp32 -> bf16 bits (RNE)
  u32 u = __float_as_uint(f);
  return (u + 0x7FFFu + ((u >> 16) & 1u)) >> 16;
}
__device__ __forceinline__ float bfbits2f(u32 b) {
  return __uint_as_float(b << 16);
}
__device__ __forceinline__ float fmed3(float a, float b, float c) {
  return __builtin_amdgcn_fmed3f(a, b, c);
}
__device__ __forceinline__ void gl_lds16(const u16* g, u16* l) {
  __builtin_amdgcn_global_load_lds(
      (const __attribute__((address_space(1))) u32*)(g),
      (__attribute__((address_space(3))) u32*)(l), 16, 0, 0);
}

// ---- prep: swizzled hi/lo bf16 codebook + exact numpy-replica b2 ----
// u16 layout: g*2048 + p*1024 + f*512 + (quad*16 + rowl)*8 + j
//   g=row>>4, rowl=row&15, p=plane(0 hi,1 lo), f=k>>5, quad=(k&31)>>3, j=k&7.
// 16B units ordered by MFMA lane id (lane = quad*16+rowl) -> LDS staging is
// a linear copy and the LDS fragment read is lane-consecutive 16B.
// 128 blocks x 256 thr; b2 via shfl_xor tree == numpy pairwise-8 bit-exactly
// (proven R13, absmax 0.0).
__global__ void vq_prep(const float* __restrict__ emb, u16* __restrict__ swz,
                        float* __restrict__ b2) {
#pragma clang fp contract(off)
  const int gtid = blockIdx.x * 256 + threadIdx.x;  // 0..32767
  {  // swz element task
    const int row = gtid >> 6, k = gtid & 63;
    const float ev = emb[gtid];
    const u32 h = f2bfbits(ev);
    const float res = ev - bfbits2f(h);  // exact (Sterbenz)
    const int g = row >> 4, rowl = row & 15;
    const int f = k >> 5, q = (k & 31) >> 3, j = k & 7;
    u16* gb = swz + (g << 11) + (f << 9) + (((q << 4) + rowl) << 3) + j;
    gb[0] = (u16)h;                     // hi plane (p=0)
    gb[1024] = (u16)f2bfbits(res);      // lo plane (p=1)
  }
  if (gtid < NEMB * 8) {  // b2 task: row = gtid>>3, j = gtid&7
    const int row = gtid >> 3, j = gtid & 7;
    const float* e = emb + (row << 6);
    float acc = e[j] * e[j];
#pragma unroll
    for (int i = 8; i < DIM; i += 8) acc = acc + e[i + j] * e[i + j];
    acc = acc + __shfl_xor(acc, 1);  // j=0: rr0+rr1
    acc = acc + __shfl_xor(acc, 2);  // j=0: (rr0+rr1)+(rr2+rr3)
    acc = acc + __shfl_xor(acc, 4);  // j=0: full pairwise-8 combine
    if (j == 0) b2[row] = acc;
  }
}

// ---- main kernel: 64 rows/block.
// wave wv: row-half rh=wv&1 (tiles 2rh,2rh+1), col-half ch=wv>>1 (256 cols).
// Codebook LDS-staged: 8 chunks x 32 cols (both halves), double-buffered.
__global__ __launch_bounds__(256, 1) void vq_mfma(
    const float* __restrict__ in, const float* __restrict__ emb,
    const u16* __restrict__ swz, const float* __restrict__ b2g,
    float* __restrict__ out) {
#pragma clang fp contract(off)
  __shared__ float xs[ROWS][DIM + 2];
  __shared__ float a2s[ROWS];
  __shared__ float b2s[NEMB];
  __shared__ float wsv1[ROWS][2], wsv2[ROWS][2], wsv3[ROWS][2];
  __shared__ int win[ROWS];
  __shared__ int queue[ROWS];
  __shared__ int qcnt;
  __shared__ u16 cb[2][8192];  // [buf][ch*4096 + gl*2048 + p*1024 + f*512 + lane*8]

  const int tid = threadIdx.x;
  const int lane = tid & 63;
  const int wv = tid >> 6;
  const int rh = wv & 1;   // row-half
  const int ch = wv >> 1;  // col-half
  const int rowl = lane & 15;
  const int quad = lane >> 4;

  const int blk = blockIdx.x;
  const int b = blk >> 6;
  const int hw0 = (blk & 63) << 6;
  const float* xbase = in + ((size_t)b << 18) + hw0;

  for (int i = tid; i < NEMB; i += 256) b2s[i] = b2g[i];
  if (tid == 0) qcnt = 0;

  // async-stage chunk 0 into buf 0 (linear copy: 16 segs of 1KB, 4 per wave)
#define VQ_STAGE(CC, BB)                                                      \
  _Pragma("unroll") for (int i_ = 0; i_ < 4; ++i_) {                          \
    const int seg = (i_ << 2) + wv; /* 0..15 */                               \
    const int ch2 = seg >> 3, s7 = seg & 7;                                   \
    gl_lds16(swz + (((ch2 << 4) + ((CC) << 1)) << 11) + (s7 << 9) + (lane << 3), \
             &cb[BB][seg << 9]);                                              \
  }
  VQ_STAGE(0, 0)

  {  // stage x tile (64 consecutive floats per wave = coalesced)
    const int h = tid & 63, cg = tid >> 6;
#pragma unroll
    for (int i = 0; i < 16; ++i) {
      const int c = cg + (i << 2);
      xs[h][c] = xbase[((size_t)c << 12) + h];
    }
  }
  __syncthreads();  // xs + chunk0 ready (drains vmcnt incl. global_load_lds)

  if (tid < ROWS) {  // a2 numpy pairwise-8 replica (re-rank input)
    const float* x = xs[tid];
    float rr[8];
#pragma unroll
    for (int j = 0; j < 8; ++j) {
      float acc = x[j] * x[j];
#pragma unroll
      for (int i = 8; i < DIM; i += 8) acc = acc + x[i + j] * x[i + j];
      rr[j] = acc;
    }
    a2s[tid] = ((rr[0] + rr[1]) + (rr[2] + rr[3])) + ((rr[4] + rr[5]) + (rr[6] + rr[7]));
  }

  // A fragments for this wave's 2 row-tiles: A[m=lane&15][k=quad*8+j]
  bf16x8 ah[2][2], al[2][2];
#pragma unroll
  for (int ta = 0; ta < 2; ++ta) {
    const int a = (rh << 1) + ta;
    const float* xr = xs[(a << 4) + rowl];
#pragma unroll
    for (int f = 0; f < 2; ++f) {
      const int k0 = (f << 5) + (quad << 3);
      bf16x8 vh, vl;
#pragma unroll
      for (int j = 0; j < 8; ++j) {
        const float xv = xr[k0 + j];
        const u32 h = f2bfbits(xv);
        const float res = xv - bfbits2f(h);  // exact
        vh[j] = (short)h;
        vl[j] = (short)f2bfbits(res);
      }
      ah[ta][f] = vh;
      al[ta][f] = vl;
    }
  }

  // ---- 8 chunks x 2 groups: streaming top-3 MAXIMA of acc' = dot - b2/2,
  // index packed in low 9 mantissa bits; codebook read from LDS ----
  float v1[8], v2[8], v3[8];
#pragma unroll
  for (int i = 0; i < 8; ++i) { v1[i] = -3.0e38f; v2[i] = -3.0e38f; v3[i] = -3.0e38f; }

#pragma unroll 1
  for (int cc = 0; cc < 8; ++cc) {
    const int bb = cc & 1;
    if (cc < 7) { VQ_STAGE(cc + 1, bb ^ 1) }  // async prefetch next chunk
#pragma unroll
    for (int gl = 0; gl < 2; ++gl) {
      const u16* fb = &cb[bb][(ch << 12) + (gl << 11)];
      const bf16x8 bh0 = *(const bf16x8*)(fb + (lane << 3));
      const bf16x8 bh1 = *(const bf16x8*)(fb + 512 + (lane << 3));
      const bf16x8 bl0 = *(const bf16x8*)(fb + 1024 + (lane << 3));
      const bf16x8 bl1 = *(const bf16x8*)(fb + 1536 + (lane << 3));
      const int n = (ch << 8) + (cc << 5) + (gl << 4) + rowl;
      const float nb2 = b2s[n] * -0.5f;
      const u32 nbits = (u32)n;
#pragma unroll
      for (int ta = 0; ta < 2; ++ta) {
        f32x4 accA = {nb2, nb2, nb2, nb2};
        f32x4 accB = {0.f, 0.f, 0.f, 0.f};
        accA = __builtin_amdgcn_mfma_f32_16x16x32_bf16(ah[ta][0], bh0, accA, 0, 0, 0);
        accB = __builtin_amdgcn_mfma_f32_16x16x32_bf16(ah[ta][1], bh1, accB, 0, 0, 0);
        accA = __builtin_amdgcn_mfma_f32_16x16x32_bf16(ah[ta][0], bl0, accA, 0, 0, 0);
        accB = __builtin_amdgcn_mfma_f32_16x16x32_bf16(ah[ta][1], bl1, accB, 0, 0, 0);
        accA = __builtin_amdgcn_mfma_f32_16x16x32_bf16(al[ta][0], bh0, accA, 0, 0, 0);
        accB = __builtin_amdgcn_mfma_f32_16x16x32_bf16(al[ta][1], bh1, accB, 0, 0, 0);
#pragma unroll
        for (int r = 0; r < 4; ++r) {
          const int i = (ta << 2) + r;
          const float c2 = accA[r] + accB[r];
          const float cp =
              __uint_as_float((__float_as_uint(c2) & 0xFFFFFE00u) | nbits);
          v3[i] = fmed3(v2[i], cp, v3[i]);
          v2[i] = fmed3(v1[i], cp, v2[i]);
          v1[i] = fmaxf(v1[i], cp);
        }
      }
    }
    __syncthreads();  // chunk cc done by all; chunk cc+1 staged
  }
#undef VQ_STAGE

  // butterfly top-3 merge across the 16 column lanes (max domain); packed
  // values carry their indices, so the merge is pure med3/max
#pragma unroll
  for (int m = 1; m < 16; m <<= 1) {
#pragma unroll
    for (int i = 0; i < 8; ++i) {
      const float o1 = __shfl_xor(v1[i], m);
      const float o2 = __shfl_xor(v2[i], m);
      const float o3 = __shfl_xor(v3[i], m);
      v3[i] = fmed3(v2[i], o1, v3[i]);
      v2[i] = fmed3(v1[i], o1, v2[i]);
      v1[i] = fmaxf(v1[i], o1);
      v3[i] = fmed3(v2[i], o2, v3[i]);
      v2[i] = fmed3(v1[i], o2, v2[i]);
      v3[i] = fmaxf(v3[i], o3);
    }
  }
  if (rowl == 0) {  // publish per col-half slot
#pragma unroll
    for (int ta = 0; ta < 2; ++ta)
#pragma unroll
      for (int r = 0; r < 4; ++r) {
        const int row = (((rh << 1) + ta) << 4) + (quad << 2) + r;
        const int i = (ta << 2) + r;
        wsv1[row][ch] = v1[i]; wsv2[row][ch] = v2[i]; wsv3[row][ch] = v3[i];
      }
  }
  __syncthreads();

  // ---- cross-half merge + decision (max domain) ----
  if (tid < ROWS) {
    float m1 = wsv1[tid][0], m2v = wsv2[tid][0], m3 = wsv3[tid][0];
    const float u1 = wsv1[tid][1], u2 = wsv2[tid][1], u3 = wsv3[tid][1];
    m3 = fmed3(m2v, u1, m3);
    m2v = fmed3(m1, u1, m2v);
    m1 = fmaxf(m1, u1);
    m3 = fmed3(m2v, u2, m3);
    m2v = fmed3(m1, u2, m2v);
    m3 = fmaxf(m3, u3);
    const int j1 = (int)(__float_as_uint(m1) & 0x1FFu);
    const int j2 = (int)(__float_as_uint(m2v) & 0x1FFu);

    if (m2v < m1 - HMARGIN) {
      win[tid] = j1;  // unambiguous
    } else if (m3 < m1 - HMARGIN) {
      // true argmin in {j1,j2}: exact numpy fp32 re-rank, first-min tie rule
      const float a2 = a2s[tid];
      const float* x = xs[tid];
      const float* e1p = emb + (j1 << 6);
      const float* e2p = emb + (j2 << 6);
      float acc1 = 0.f, acc2 = 0.f;
#pragma unroll
      for (int j = 0; j < DIM; ++j) {
        acc1 = fmaf(x[j], e1p[j], acc1);
        acc2 = fmaf(x[j], e2p[j], acc2);
      }
      const float t1 = a2 + b2s[j1];
      const float t2 = a2 + b2s[j2];
      const float d1 = t1 - 2.0f * acc1;
      const float d2 = t2 - 2.0f * acc2;
      win[tid] = (d2 < d1 || (d2 == d1 && j2 < j1)) ? j2 : j1;
    } else {  // >=3 within margin: full exact rescan (rare)
      const int p = atomicAdd(&qcnt, 1);
      queue[p] = tid;
    }
  }
  __syncthreads();

  // ---- rare fallback: wave-cooperative bit-exact numpy fp32 rescan ----
  const int nq = qcnt;
  for (int qi = wv; qi < nq; qi += 4) {
    const int row = queue[qi];
    const float a2 = a2s[row];
    const float* x = xs[row];  // broadcast LDS reads
    float bd = 3.0e38f;
    int bi = 1 << 30;
#pragma unroll 1
    for (int c = 0; c < 8; ++c) {
      const int k = (c << 6) + lane;
      const float* e = emb + (k << 6);
      float acc = 0.f;
#pragma unroll
      for (int j = 0; j < DIM; ++j) acc = fmaf(x[j], e[j], acc);
      const float tt = a2 + b2s[k];  // fl(a2+b2)
      const float u = 2.0f * acc;    // fl(2ab)
      const float d = tt - u;        // fl(t-u)
      if (d < bd || (d == bd && k < bi)) { bd = d; bi = k; }
    }
#pragma unroll
    for (int m = 1; m < 64; m <<= 1) {  // numpy first-min tie rule
      const float od = __shfl_xor(bd, m);
      const int oi = __shfl_xor(bi, m);
      if (od < bd || (od == bd && oi < bi)) { bd = od; bi = oi; }
    }
    if (lane == 0) win[row] = bi;
  }
  __syncthreads();

  {  // fold q into xs in place: batched (16 concurrent emb-row loads)
    const int r0 = wv << 4;
    int wn[16];
#pragma unroll
    for (int r = 0; r < 16; ++r) wn[r] = win[r0 + r];
    float qv[16];
#pragma unroll
    for (int r = 0; r < 16; ++r) qv[r] = emb[(wn[r] << 6) + lane];
#pragma unroll
    for (int r = 0; r < 16; ++r) {
      const float xv = xs[r0 + r][lane];
      xs[r0 + r][lane] = xv + (qv[r] - xv);  // fl(x + fl(q-x))
    }
  }
  __syncthreads();

  {  // store: coalesced (lane = h)
    const int h = tid & 63, cg = tid >> 6;
    float* obase = out + ((size_t)b << 18) + hw0;
#pragma unroll
    for (int i = 0; i < 16; ++i) {
      const int c = cg + (i << 2);
      obase[((size_t)c << 12) + h] = xs[h][c];
    }
  }
}

// ---- fallback (R3, passed absmax 0.0): used only if ws too small ----
__global__ __launch_bounds__(256, 2) void vq_exact(
    const float* __restrict__ in, const float* __restrict__ emb,
    float* __restrict__ out, int nvec) {
#pragma clang fp contract(off)
  __shared__ float b2s[NEMB];
  for (int r = threadIdx.x; r < NEMB; r += 256) {
    const float* e = emb + r * DIM;
    float rr[8];
#pragma unroll
    for (int j = 0; j < 8; ++j) {
      float acc = e[j] * e[j];
#pragma unroll
      for (int i = 8; i < DIM; i += 8) acc = acc + e[i + j] * e[i + j];
      rr[j] = acc;
    }
    b2s[r] = ((rr[0] + rr[1]) + (rr[2] + rr[3])) + ((rr[4] + rr[5]) + (rr[6] + rr[7]));
  }
  __syncthreads();
  const int vec = blockIdx.x * 256 + threadIdx.x;
  if (vec >= nvec) return;
  const int b = vec >> 12, hw = vec & 4095;
  const float* xp = in + ((size_t)b << 18) + hw;
  float x[DIM];
#pragma unroll
  for (int j = 0; j < DIM; ++j) x[j] = xp[(size_t)j << 12];
  float a2;
  {
    float rr[8];
#pragma unroll
    for (int j = 0; j < 8; ++j) {
      float acc = x[j] * x[j];
#pragma unroll
      for (int i = 8; i < DIM; i += 8) acc = acc + x[i + j] * x[i + j];
      rr[j] = acc;
    }
    a2 = ((rr[0] + rr[1]) + (rr[2] + rr[3])) + ((rr[4] + rr[5]) + (rr[6] + rr[7]));
  }
  float best = 3.0e38f;
  int bi = 0;
  for (int k0 = 0; k0 < NEMB; k0 += 4) {
    const float *e0 = emb + ((k0 + 0) << 6), *e1 = emb + ((k0 + 1) << 6);
    const float *e2 = emb + ((k0 + 2) << 6), *e3 = emb + ((k0 + 3) << 6);
    float c0 = 0.f, c1 = 0.f, c2 = 0.f, c3 = 0.f;
#pragma unroll
    for (int j = 0; j < DIM; ++j) {
      const float xj = x[j];
      c0 = fmaf(xj, e0[j], c0); c1 = fmaf(xj, e1[j], c1);
      c2 = fmaf(xj, e2[j], c2); c3 = fmaf(xj, e3[j], c3);
    }
    float cc[4] = {c0, c1, c2, c3};
#pragma unroll
    for (int q = 0; q < 4; ++q) {
      const float t = a2 + b2s[k0 + q];
      const float u = 2.0f * cc[q];
      const float d = t - u;
      if (d < best) { best = d; bi = k0 + q; }
    }
  }
  const float* ew = emb + (bi << 6);
  float* op = out + ((size_t)b << 18) + hw;
#pragma unroll
  for (int c = 0; c < DIM; ++c) {
    const float xv = x[c];
    op[(size_t)c << 12] = xv + (ew[c] - xv);
  }
}

extern "C" void kernel_launch(void* const* d_in, const int* in_sizes, int n_in,
                              void* d_out, int out_size, void* d_ws, size_t ws_size,
                              hipStream_t stream) {
  const float* in;
  const float* emb;
  int in_elems;
  if (n_in >= 2 && in_sizes[0] == NEMB * DIM && in_sizes[1] != NEMB * DIM) {
    emb = (const float*)d_in[0]; in = (const float*)d_in[1]; in_elems = in_sizes[1];
  } else {
    in = (const float*)d_in[0]; emb = (const float*)d_in[1]; in_elems = in_sizes[0];
  }
  float* out = (float*)d_out;
  const int nvec = in_elems / DIM;
  const size_t swzB = (size_t)NEMB * DIM * 2 * sizeof(u16);  // hi+lo swizzled
  const size_t need = swzB + NEMB * sizeof(float);

  if (ws_size >= need && d_ws != nullptr && (nvec % ROWS) == 0 &&
      (in_elems % (DIM * 4096)) == 0) {
    u16* swz = (u16*)d_ws;
    float* b2 = (float*)((char*)d_ws + swzB);
    vq_prep<<<dim3(NEMB * DIM / 256), dim3(256), 0, stream>>>(emb, swz, b2);
    vq_mfma<<<dim3(nvec / ROWS), dim3(256), 0, stream>>>(in, emb, swz, b2, out);
  } else {
    vq_exact<<<dim3((nvec + 255) / 256), dim3(256), 0, stream>>>(in, emb, out, nvec);
  }
}